// Round 3
// baseline (898.926 us; speedup 1.0000x reference)
//
#include <hip/hip_runtime.h>
#include <hip/hip_bf16.h>

// y_n = tanh(W_n @ sum_k values[idx[n,k]] + b_n);  M=1e6, D=16, N=500000, K=8.
//
// Fully fused, no LDS, no barriers. Thread t -> (neuron n = t/16, sublane i).
//   gather:  lane i sums element i of 8 gathered 64B rows (coalesced segments)
//   s-chunk: 4 x __shfl gives each lane s[4k..4k+3], k = i&3
//   W loads: 16-lane group reads 16 CONSECUTIVE float4 per step -> 256B dense
//            segments (vs R0/R1's 64B-strided 16B pattern)
//   reduce:  quad butterfly (shfl_xor 1,2) completes the 16 dot products
//   store:   within-segment permuted coalesced writes
//
// DIAGNOSTIC: kernel launched TWICE (idempotent). dur_us = overhead + 2*T_k
// discriminates "harness poison fills inside timed window" (~835us) vs
// "kernel-bound" (<450 or ~1400).

#define D_DIM 16
#define K_FAN 8

__global__ __launch_bounds__(256)
void WeightedAtomLayer_fused(const float* __restrict__ values,  // [M,16]
                             const int*   __restrict__ idx,     // [N,8]
                             const float* __restrict__ W,       // [N,16,16]
                             const float* __restrict__ b,       // [N,16]
                             float*       __restrict__ out,     // [N,16]
                             int N)
{
    const int gt = blockIdx.x * 256 + threadIdx.x;
    const int n  = gt >> 4;
    if (n >= N) return;
    const int i  = gt & 15;      // sublane 0..15 (same as threadIdx.x & 15)
    const int q  = i >> 2;       // quad id within group
    const int k  = i & 3;        // owned column-chunk

    // ---- gather + fan-in sum: lane i owns element i ----
    float s = 0.0f;
    const int* idxn = idx + (size_t)n * K_FAN;
    #pragma unroll
    for (int kk = 0; kk < K_FAN; ++kk) {
        const size_t row = (size_t)idxn[kk];       // L1-hot broadcast read
        s += values[row * D_DIM + i];              // 64B coalesced segment
    }

    // ---- redistribute: this lane needs s-chunk k = s[4k..4k+3] ----
    const int gbase = (threadIdx.x & 63) & ~15;    // group base lane in wave
    float4 s4;
    s4.x = __shfl(s, gbase + 4 * k + 0);
    s4.y = __shfl(s, gbase + 4 * k + 1);
    s4.z = __shfl(s, gbase + 4 * k + 2);
    s4.w = __shfl(s, gbase + 4 * k + 3);

    // ---- W: 4 loads, each = 16 consecutive float4 per 16-lane group ----
    // f4 #(c*16+i) of neuron n = row (4c+q), column-chunk k.
    const float4* Wf4 = (const float4*)(W + (size_t)n * (D_DIM * D_DIM));
    const float4 w0 = Wf4[0 * 16 + i];
    const float4 w1 = Wf4[1 * 16 + i];
    const float4 w2 = Wf4[2 * 16 + i];
    const float4 w3 = Wf4[3 * 16 + i];

    float4 p;   // p.{x,y,z,w} = partial dot for rows q, 4+q, 8+q, 12+q
    p.x = w0.x * s4.x + w0.y * s4.y + w0.z * s4.z + w0.w * s4.w;
    p.y = w1.x * s4.x + w1.y * s4.y + w1.z * s4.z + w1.w * s4.w;
    p.z = w2.x * s4.x + w2.y * s4.y + w2.z * s4.z + w2.w * s4.w;
    p.w = w3.x * s4.x + w3.y * s4.y + w3.z * s4.z + w3.w * s4.w;

    // ---- butterfly sum across the quad (lanes gbase+4q .. +3) ----
    p.x += __shfl_xor(p.x, 1);
    p.y += __shfl_xor(p.y, 1);
    p.z += __shfl_xor(p.z, 1);
    p.w += __shfl_xor(p.w, 1);
    p.x += __shfl_xor(p.x, 2);
    p.y += __shfl_xor(p.y, 2);
    p.z += __shfl_xor(p.z, 2);
    p.w += __shfl_xor(p.w, 2);

    // lane (4q+k) keeps component k -> output row r = 4k+q (bijection)
    const float y = (k == 0) ? p.x : (k == 1) ? p.y : (k == 2) ? p.z : p.w;
    const int    r = 4 * k + q;
    const size_t o = (size_t)n * D_DIM + r;
    out[o] = tanhf(y + b[o]);
}

extern "C" void kernel_launch(void* const* d_in, const int* in_sizes, int n_in,
                              void* d_out, int out_size, void* d_ws, size_t ws_size,
                              hipStream_t stream) {
    const float* values = (const float*)d_in[0];   // [M,16] fp32
    const int*   idx    = (const int*)  d_in[1];   // [N,8]  int32
    const float* W      = (const float*)d_in[2];   // [N,16,16] fp32
    const float* b      = (const float*)d_in[3];   // [N,16] fp32
    float*       out    = (float*)d_out;

    const int N = in_sizes[3] / D_DIM;             // 500000
    const int blocks = (N * D_DIM + 255) / 256;    // 31250

    // Launched TWICE on purpose this round (idempotent): dur_us delta vs a
    // single launch measures the true per-kernel cost vs fixed harness
    // overhead. Remove the duplicate next round.
    WeightedAtomLayer_fused<<<blocks, 256, 0, stream>>>(values, idx, W, b, out, N);
    WeightedAtomLayer_fused<<<blocks, 256, 0, stream>>>(values, idx, W, b, out, N);
}